// Round 8
// baseline (229.099 us; speedup 1.0000x reference)
//
#include <hip/hip_runtime.h>
#include <hip/hip_bf16.h>
#include <math.h>

#define BB 4
#define SS 512
#define HH 768
#define DD 24
#define MM 96
#define OH 768      // OUT_HID
#define K3H 2304    // 3*H

typedef unsigned short u16;
typedef unsigned int u32;
typedef short bf16x8 __attribute__((ext_vector_type(8)));
typedef float f32x4 __attribute__((ext_vector_type(4)));
typedef u16 u16x4 __attribute__((ext_vector_type(4)));

// bf16 workspace (offsets in u16 from ws base)
#define MB_MSGIN  0                            // [2048][2304]
#define MB_H1     (MB_MSGIN + BB*SS*K3H)       // [2048][768]
#define MB_W1     (MB_H1    + BB*SS*OH)        // [768][2304]
#define MB_W2     (MB_W1    + OH*K3H)          // [768][768]
#define MB_PROBS  (MB_W2    + OH*HH)           // [2048][512]
#define MB_HIT    (MB_PROBS + BB*SS*SS)        // [b][768][512]
#define MB_ZJP    (MB_HIT   + BB*HH*SS)        // [2048][32] bf16, cols>=24 zero
#define MB_ZIP    (MB_ZJP   + BB*SS*32)        // [2048][32]
#define MB_WM     (MB_ZIP   + BB*SS*32)        // [96][96] scorer W
#define MB_WAB    (MB_WM    + MM*96)           // [96][32]  Wa padded
#define MB_AB     (MB_WAB   + MM*32)           // [2048][96] A bf16

__device__ inline u16 f2bf(float x) {
    union { float f; u32 u; } v; v.f = x;
    u32 r = v.u + 0x7fffu + ((v.u >> 16) & 1u);   // RNE
    return (u16)(r >> 16);
}
__device__ inline u32 pk2bf(float lo, float hi) {
    return ((__float_as_uint(lo) + 0x8000u) >> 16) |
           ((__float_as_uint(hi) + 0x8000u) & 0xffff0000u);
}
__device__ inline void unpack8(bf16x8 v, float* f) {
    const u32* d = (const u32*)&v;
    #pragma unroll
    for (int i = 0; i < 4; ++i) {
        f[2*i]   = __uint_as_float(d[i] << 16);
        f[2*i+1] = __uint_as_float(d[i] & 0xffff0000u);
    }
}
__device__ inline void gl_lds16(const u16* g, u16* l) {
    __builtin_amdgcn_global_load_lds(
        (const __attribute__((address_space(1))) void*)g,
        (__attribute__((address_space(3))) void*)l, 16, 0, 0);
}
__device__ inline bf16x8 frag64(const u16* X, int r, int g) {
    return *(const bf16x8*)&X[(r*8 + (g ^ (r & 7)))*8];
}

// ---------------------------------------------------------------------------
// W0: tiny scorer-weight builder (must precede prep's zgemm epilogue)
// ---------------------------------------------------------------------------
__global__ __launch_bounds__(256) void k_wm(
    const float* __restrict__ sw1, u16* __restrict__ Wm, u16* __restrict__ Wab)
{
    for (int i = threadIdx.x; i < MM*96; i += 256) {
        int m = i / 96, k = i % 96;
        float v = 0.f;
        if (k < 24)                 v = sw1[m*96 + 48 + k];         // Wc
        else if (k >= 32 && k < 56) v = sw1[m*96 + 72 + (k - 32)];  // Wd
        else if (k >= 64 && k < 88) v = sw1[m*96 + 24 + (k - 64)];  // Wb
        Wm[i] = f2bf(v);
    }
    for (int i = threadIdx.x; i < MM*32; i += 256) {
        int m = i >> 5, k = i & 31;
        Wab[i] = (k < 24) ? f2bf(sw1[m*96 + k]) : (u16)0;
    }
}

// ---------------------------------------------------------------------------
// PREP (one launch, 1600 blocks):
//  [0,64)      : Z = H@P^T MFMA (j/i) + A epilogue
//  [64,928)    : cast vw1 -> w1b
//  [928,1216)  : cast vw2 -> w2b
//  [1216,1600) : transpose Hi -> HiT bf16 [b][h][t]
// (Hj cast into msgin is now fused into k_ctx_mfma's epilogue)
// ---------------------------------------------------------------------------
#define PZ_END   64
#define PC1_END  928
#define PC2_END  1216
#define PHT_END  1600

__global__ __launch_bounds__(256) void k_prep(
    const float* __restrict__ Hj, const float* __restrict__ Hi,
    const float* __restrict__ pjw, const float* __restrict__ piw,
    const float* __restrict__ sb1,
    const float* __restrict__ vw1, const float* __restrict__ vw2,
    const u16* __restrict__ Wab,
    u16* __restrict__ w1b, u16* __restrict__ w2b,
    u16* __restrict__ Zjp, u16* __restrict__ Zip, u16* __restrict__ Ab,
    u16* __restrict__ HiTb)
{
    __shared__ __align__(16) u16 smem[5120];
    int bx = blockIdx.x;
    int tid = threadIdx.x;

    if (bx < PZ_END) {
        int idx = bx;
        int isJ = (idx < 32);
        int n0 = (idx & 31) * 64;
        const float* H = isJ ? Hj : Hi;
        const float* P = isJ ? pjw : piw;
        u16* Zout = isJ ? Zjp : Zip;
        u16* As = smem;
        u16* Bs = smem + 2048;
        u16* zb = smem + 3072;
        int wave = tid >> 6, lane = tid & 63;
        int q = lane >> 4, l16 = lane & 15;

        { int i = tid; Bs[(24 + (i >> 5))*32 + (i & 31)] = 0; }

        int arow = tid >> 2, aseg = tid & 3;
        const float* ah = H + (size_t)(n0 + arow)*HH + aseg*8;
        const float* bh = P + (size_t)arow*HH + aseg*8;
        int adst = arow*32 + ((aseg ^ (arow & 3))*8);

        float4 xa = *(const float4*)(ah);
        float4 ya = *(const float4*)(ah + 4);
        float4 xb = {}, yb = {};
        if (tid < 96) { xb = *(const float4*)(bh); yb = *(const float4*)(bh + 4); }

        f32x4 acc0 = {}, acc1 = {};
        int ga = q ^ (l16 & 3);
        for (int k0 = 0; k0 < HH; k0 += 32) {
            { u32* w = (u32*)&As[adst];
              w[0] = pk2bf(xa.x, xa.y); w[1] = pk2bf(xa.z, xa.w);
              w[2] = pk2bf(ya.x, ya.y); w[3] = pk2bf(ya.z, ya.w); }
            if (tid < 96) {
              u32* w = (u32*)&Bs[adst];
              w[0] = pk2bf(xb.x, xb.y); w[1] = pk2bf(xb.z, xb.w);
              w[2] = pk2bf(yb.x, yb.y); w[3] = pk2bf(yb.z, yb.w); }
            float4 nxa = {}, nya = {}, nxb = {}, nyb = {};
            if (k0 + 32 < HH) {
                nxa = *(const float4*)(ah + k0 + 32);
                nya = *(const float4*)(ah + k0 + 36);
                if (tid < 96) { nxb = *(const float4*)(bh + k0 + 32);
                                nyb = *(const float4*)(bh + k0 + 36); }
            }
            __syncthreads();
            bf16x8 af = *(const bf16x8*)&As[(wave*16 + l16)*32 + ga*8];
            bf16x8 b0 = *(const bf16x8*)&Bs[l16*32 + ga*8];
            bf16x8 b1 = *(const bf16x8*)&Bs[(16 + l16)*32 + ga*8];
            acc0 = __builtin_amdgcn_mfma_f32_16x16x32_bf16(af, b0, acc0, 0,0,0);
            acc1 = __builtin_amdgcn_mfma_f32_16x16x32_bf16(af, b1, acc1, 0,0,0);
            __syncthreads();
            xa = nxa; ya = nya; xb = nxb; yb = nyb;
        }
        #pragma unroll
        for (int r = 0; r < 4; ++r) {
            zb[(wave*16 + q*4 + r)*32 + l16]      = f2bf(acc0[r]);
            zb[(wave*16 + q*4 + r)*32 + 16 + l16] = f2bf(acc1[r]);
        }
        __syncthreads();
        { uint4 v = *(const uint4*)&zb[tid*8];
          *(uint4*)&Zout[(size_t)n0*32 + tid*8] = v; }
        if (isJ) {
            bf16x8 af = *(const bf16x8*)&zb[(wave*16 + l16)*32 + q*8];
            #pragma unroll
            for (int nt = 0; nt < 6; ++nt) {
                bf16x8 bw = *(const bf16x8*)&Wab[(nt*16 + l16)*32 + q*8];
                f32x4 a = {};
                a = __builtin_amdgcn_mfma_f32_16x16x32_bf16(af, bw, a, 0,0,0);
                float bv = sb1[nt*16 + l16];
                #pragma unroll
                for (int r = 0; r < 4; ++r) {
                    int bs = n0 + wave*16 + q*4 + r;
                    Ab[(size_t)bs*MM + nt*16 + l16] = f2bf(a[r] + bv);
                }
            }
        }
    } else if (bx < PC2_END) {
        int idx; const float* src; u16* dst;
        if (bx < PC1_END) { idx = bx - PZ_END;  src = vw1; dst = w1b; }
        else              { idx = bx - PC1_END; src = vw2; dst = w2b; }
        int i = (idx*256 + tid) * 8;
        float4 a = *(const float4*)&src[i];
        float4 c = *(const float4*)&src[i+4];
        u16x4 lo = { f2bf(a.x), f2bf(a.y), f2bf(a.z), f2bf(a.w) };
        u16x4 hi = { f2bf(c.x), f2bf(c.y), f2bf(c.z), f2bf(c.w) };
        *(u16x4*)&dst[i]   = lo;
        *(u16x4*)&dst[i+4] = hi;
    } else {
        int idx = bx - PC2_END;
        int t0 = (idx & 7) * 64;
        int h0 = ((idx >> 3) % 12) * 64;
        int b  = idx / 96;
        u16* tile = smem;                          // 64*74 = 4736 u16
        int r = tid >> 2, cs = tid & 3;
        const float* src = Hi + ((size_t)(b*SS) + t0 + r)*HH + h0 + cs*16;
        u16* dst = &tile[r*74 + cs*16];
        #pragma unroll
        for (int i = 0; i < 4; ++i) {
            float4 v = *(const float4*)(src + i*4);
            *(u32*)&dst[i*4]     = pk2bf(v.x, v.y);
            *(u32*)&dst[i*4 + 2] = pk2bf(v.z, v.w);
        }
        __syncthreads();
        int hr = tid >> 2;
        u16 outv[16];
        #pragma unroll
        for (int i = 0; i < 16; ++i) outv[i] = tile[(cs*16 + i)*74 + hr];
        u16* o = HiTb + ((size_t)b*HH + h0 + hr)*SS + t0 + cs*16;
        *(uint4*)o       = *(const uint4*)&outv[0];
        *(uint4*)(o + 8) = *(const uint4*)&outv[8];
    }
}

// ---------------------------------------------------------------------------
// K2: register-fragment MFMA pairwise scorer + softmax (unchanged).
// ---------------------------------------------------------------------------
__global__ __launch_bounds__(256) void k_pair_mfma(
    const u16* __restrict__ Zjp, const u16* __restrict__ Zip,
    const u16* __restrict__ Ab, const u16* __restrict__ Wm,
    const float* __restrict__ sw2, const float* __restrict__ mask,
    u16* __restrict__ probsb)
{
    int blk = blockIdx.x; int b = blk >> 8; int s0 = (blk & 255) * 2;
    int tid = threadIdx.x, wave = tid >> 6, lane = tid & 63;
    int q = lane >> 4, l16 = lane & 15;
    int si = wave & 1, half = wave >> 1;
    int s = s0 + si, bs = b*SS + s;
    __shared__ __align__(16) u16 ZiS[SS*32];
    __shared__ float logits[2][SS];

    {
        const u16* zb = Zip + (size_t)b*SS*32;
        #pragma unroll
        for (int p = 0; p < 8; ++p) {
            int idx = p*256 + tid;
            int t = idx >> 2, c = idx & 3;
            int g = c ^ ((t + (t >> 2)) & 3);
            gl_lds16(zb + t*32 + g*8, ZiS + idx*8);
        }
    }

    bf16x8 zjf = *(const bf16x8*)&Zjp[(size_t)bs*32 + q*8];
    float zj[8]; unpack8(zjf, zj);
    bf16x8 afc[6], afd[6];
    #pragma unroll
    for (int mt = 0; mt < 6; ++mt) {
        const u16* wrow = &Wm[(mt*16 + l16)*96];
        bf16x8 wcf = *(const bf16x8*)&wrow[q*8];
        afd[mt]    = *(const bf16x8*)&wrow[32 + q*8];
        bf16x8 wbf = *(const bf16x8*)&wrow[64 + q*8];
        float fc[8], fb[8];
        unpack8(wcf, fc); unpack8(wbf, fb);
        u32 aval = (u32)Ab[(size_t)bs*MM + mt*16 + l16];
        union { u32 d[4]; bf16x8 v; } pk;
        #pragma unroll
        for (int i = 0; i < 4; ++i)
            pk.d[i] = pk2bf(fmaf(fc[2*i], zj[2*i], fb[2*i]),
                            fmaf(fc[2*i+1], zj[2*i+1], fb[2*i+1]));
        pk.d[0] = (q == 3) ? aval : pk.d[0];
        afc[mt] = pk.v;
    }
    float w2v[6][4];
    #pragma unroll
    for (int mt = 0; mt < 6; ++mt)
        #pragma unroll
        for (int r = 0; r < 4; ++r) w2v[mt][r] = sw2[mt*16 + q*4 + r];

    __syncthreads();

    for (int k = 0; k < 16; ++k) {
        int t0 = (half*16 + k) * 16;
        int trow = t0 + l16;
        int sw = q ^ ((trow + (trow >> 2)) & 3);
        bf16x8 zif = *(const bf16x8*)&ZiS[trow*32 + sw*8];
        float zi[8]; unpack8(zif, zi);
        union { u32 d[4]; bf16x8 v; } b1, b2;
        #pragma unroll
        for (int i = 0; i < 4; ++i)
            b1.d[i] = pk2bf(fabsf(zj[2*i] - zi[2*i]), fabsf(zj[2*i+1] - zi[2*i+1]));
        b2.v = zif;
        b2.d[0] = (q == 3) ? 0x3F80u : b2.d[0];
        f32x4 acc[6];
        #pragma unroll
        for (int mt = 0; mt < 6; ++mt) {
            f32x4 a = {};
            a = __builtin_amdgcn_mfma_f32_16x16x32_bf16(afc[mt], b2.v, a, 0,0,0);
            a = __builtin_amdgcn_mfma_f32_16x16x32_bf16(afd[mt], b1.v, a, 0,0,0);
            acc[mt] = a;
        }
        float p = 0.f;
        #pragma unroll
        for (int mt = 0; mt < 6; ++mt)
            #pragma unroll
            for (int r = 0; r < 4; ++r)
                p = fmaf(fmaxf(acc[mt][r], 0.f), w2v[mt][r], p);
        p += __shfl_xor(p, 16);
        p += __shfl_xor(p, 32);
        if (lane < 16) logits[si][t0 + lane] = p;
    }
    __syncthreads();

    if (wave < 2) {
        const float NEGF = -3.4028234663852886e38f;
        int bss = b*SS + s0 + wave;
        float l[8], e[8];
        float mx = -INFINITY;
        #pragma unroll
        for (int i = 0; i < 8; ++i) {
            int idx = lane + i*64;
            l[i] = logits[wave][idx] + (1.f - mask[b*SS + idx]) * NEGF;
            mx = fmaxf(mx, l[i]);
        }
        #pragma unroll
        for (int off = 32; off > 0; off >>= 1) mx = fmaxf(mx, __shfl_xor(mx, off));
        float sum = 0.f;
        #pragma unroll
        for (int i = 0; i < 8; ++i) { e[i] = __expf(l[i] - mx); sum += e[i]; }
        #pragma unroll
        for (int off = 32; off > 0; off >>= 1) sum += __shfl_xor(sum, off);
        float inv = 1.f / sum;
        #pragma unroll
        for (int i = 0; i < 8; ++i)
            probsb[(size_t)bss*SS + lane + i*64] = f2bf(e[i] * inv);
    }
}

// ---------------------------------------------------------------------------
// K3: ctx via MFMA, 64x64 tile, BK=64.  A (probs) staged in LDS; B (HiT)
// fragments loaded DIRECTLY from global (L2-hot) -- halves LDS traffic.
// Epilogue: LDS remap + direct fp32 Hj read -> writes ctx|Hj|ctx*Hj thirds.
// ---------------------------------------------------------------------------
__global__ __launch_bounds__(256) void k_ctx_mfma(
    const u16* __restrict__ probsb, const u16* __restrict__ HiTb,
    const float* __restrict__ Hj, u16* __restrict__ msginb)
{
    int b = blockIdx.z;
    int h0 = blockIdx.x * 64;
    int s0 = blockIdx.y * 64;
    int tid = threadIdx.x;
    __shared__ __align__(16) u16 smem[4608];      // As (4096) reused as zb (4608)
    u16* As = smem;
    int wave = tid >> 6, lane = tid & 63;
    int wr = (wave >> 1) * 32, wc = (wave & 1) * 32;
    int q = lane >> 4, l16 = lane & 15;
    f32x4 acc[2][2] = {};
    const u16* ag = probsb + ((size_t)(b*SS) + s0)*SS;
    const u16* bg0 = HiTb + ((size_t)b*HH + h0 + wc + l16)*SS + q*8;
    const u16* bg1 = bg0 + (size_t)16*SS;
    for (int k0 = 0; k0 < SS; k0 += 64) {
        #pragma unroll
        for (int p = 0; p < 2; ++p) {
            int sl = p*256 + tid; int rr = sl >> 3, gi = sl & 7, g = gi ^ (rr & 7);
            gl_lds16(ag + (size_t)rr*SS + k0 + g*8, As + sl*8);
        }
        __syncthreads();
        #pragma unroll
        for (int ks = 0; ks < 2; ++ks) {
            int g = ks*4 + q;
            bf16x8 a0 = frag64(As, wr + l16, g);
            bf16x8 a1 = frag64(As, wr + 16 + l16, g);
            bf16x8 b0 = *(const bf16x8*)(bg0 + k0 + ks*32);
            bf16x8 b1 = *(const bf16x8*)(bg1 + k0 + ks*32);
            acc[0][0] = __builtin_amdgcn_mfma_f32_16x16x32_bf16(a0, b0, acc[0][0], 0,0,0);
            acc[0][1] = __builtin_amdgcn_mfma_f32_16x16x32_bf16(a0, b1, acc[0][1], 0,0,0);
            acc[1][0] = __builtin_amdgcn_mfma_f32_16x16x32_bf16(a1, b0, acc[1][0], 0,0,0);
            acc[1][1] = __builtin_amdgcn_mfma_f32_16x16x32_bf16(a1, b1, acc[1][1], 0,0,0);
        }
        __syncthreads();
    }
    u16* zb = smem;   // stride 72 u16 (16B-aligned rows)
    #pragma unroll
    for (int rt = 0; rt < 2; ++rt)
        #pragma unroll
        for (int ct = 0; ct < 2; ++ct) {
            int hl = wc + ct*16 + l16;
            #pragma unroll
            for (int r = 0; r < 4; ++r)
                zb[(wr + rt*16 + q*4 + r)*72 + hl] = f2bf(acc[rt][ct][r]);
        }
    __syncthreads();
    {
        int s_l = tid >> 2, seg = tid & 3;
        u16 cv[16], hv[16], pv[16];
        *(uint4*)&cv[0] = *(const uint4*)&zb[s_l*72 + seg*16];
        *(uint4*)&cv[8] = *(const uint4*)&zb[s_l*72 + seg*16 + 8];
        int hc = h0 + seg*16;
        const float* hj = Hj + ((size_t)(b*SS) + s0 + s_l)*HH + hc;
        float hf[16];
        #pragma unroll
        for (int i = 0; i < 4; ++i) *(float4*)&hf[i*4] = *(const float4*)(hj + i*4);
        #pragma unroll
        for (int i = 0; i < 8; ++i) {
            float c0 = __uint_as_float((u32)cv[2*i] << 16);
            float c1 = __uint_as_float((u32)cv[2*i+1] << 16);
            u32 hr = pk2bf(hf[2*i], hf[2*i+1]);
            hv[2*i] = (u16)hr; hv[2*i+1] = (u16)(hr >> 16);
            float g0 = __uint_as_float((u32)hv[2*i] << 16);
            float g1 = __uint_as_float((u32)hv[2*i+1] << 16);
            u32 pr = pk2bf(c0*g0, c1*g1);
            pv[2*i] = (u16)pr; pv[2*i+1] = (u16)(pr >> 16);
        }
        u16* row = msginb + (size_t)(b*SS + s0 + s_l)*K3H;
        *(uint4*)&row[hc]            = *(const uint4*)&cv[0];
        *(uint4*)&row[hc + 8]        = *(const uint4*)&cv[8];
        *(uint4*)&row[HH + hc]       = *(const uint4*)&hv[0];
        *(uint4*)&row[HH + hc + 8]   = *(const uint4*)&hv[8];
        *(uint4*)&row[2*HH + hc]     = *(const uint4*)&pv[0];
        *(uint4*)&row[2*HH + hc + 8] = *(const uint4*)&pv[8];
    }
}

// ---------------------------------------------------------------------------
// G1: h1 = relu(msgin @ w1^T + vb1) -> bf16.  64x64, BK=64, A in LDS,
// B fragments direct from global (L2-hot weights).
// ---------------------------------------------------------------------------
__global__ __launch_bounds__(256) void k_mfma_gemm1(
    const u16* __restrict__ Abf, const u16* __restrict__ Bbf,
    const float* __restrict__ bias, u16* __restrict__ Cbf)
{
    int o0 = blockIdx.x * 64;
    int n0 = blockIdx.y * 64;
    int tid = threadIdx.x;
    __shared__ __align__(16) u16 As[64*64];
    int wave = tid >> 6, lane = tid & 63;
    int wr = (wave >> 1) * 32, wc = (wave & 1) * 32;
    int q = lane >> 4, l16 = lane & 15;
    f32x4 acc[2][2] = {};
    const u16* ag = Abf + (size_t)n0*K3H;
    const u16* bg0 = Bbf + (size_t)(o0 + wc + l16)*K3H + q*8;
    const u16* bg1 = bg0 + (size_t)16*K3H;
    for (int k0 = 0; k0 < K3H; k0 += 64) {
        #pragma unroll
        for (int p = 0; p < 2; ++p) {
            int sl = p*256 + tid; int rr = sl >> 3, gi = sl & 7, g = gi ^ (rr & 7);
            gl_lds16(ag + (size_t)rr*K3H + k0 + g*8, As + sl*8);
        }
        __syncthreads();
        #pragma unroll
        for (int ks = 0; ks < 2; ++ks) {
            int g = ks*4 + q;
            bf16x8 a0 = frag64(As, wr + l16, g);
            bf16x8 a1 = frag64(As, wr + 16 + l16, g);
            bf16x8 b0 = *(const bf16x8*)(bg0 + k0 + ks*32);
            bf16x8 b1 = *(const bf16x8*)(bg1 + k0 + ks*32);
            acc[0][0] = __builtin_amdgcn_mfma_f32_16x16x32_bf16(a0, b0, acc[0][0], 0,0,0);
            acc[0][1] = __builtin_amdgcn_mfma_f32_16x16x32_bf16(a0, b1, acc[0][1], 0,0,0);
            acc[1][0] = __builtin_amdgcn_mfma_f32_16x16x32_bf16(a1, b0, acc[1][0], 0,0,0);
            acc[1][1] = __builtin_amdgcn_mfma_f32_16x16x32_bf16(a1, b1, acc[1][1], 0,0,0);
        }
        __syncthreads();
    }
    #pragma unroll
    for (int rt = 0; rt < 2; ++rt) {
        #pragma unroll
        for (int ct = 0; ct < 2; ++ct) {
            int o = o0 + wc + ct*16 + l16;
            float bv = bias[o];
            #pragma unroll
            for (int r = 0; r < 4; ++r) {
                int m = n0 + wr + rt*16 + q*4 + r;
                Cbf[(size_t)m*OH + o] = f2bf(fmaxf(acc[rt][ct][r] + bv, 0.f));
            }
        }
    }
}

// ---------------------------------------------------------------------------
// G2: out = alpha * (h1 @ w2^T + vb2).  64x64, BK=64, B direct from global.
// ---------------------------------------------------------------------------
__global__ __launch_bounds__(256) void k_mfma_gemm2(
    const u16* __restrict__ Abf, const u16* __restrict__ Bbf,
    const float* __restrict__ bias, const float* __restrict__ alpha,
    float* __restrict__ out)
{
    int o0 = blockIdx.x * 64;
    int n0 = blockIdx.y * 64;
    int tid = threadIdx.x;
    __shared__ __align__(16) u16 As[64*64];
    int wave = tid >> 6, lane = tid & 63;
    int wr = (wave >> 1) * 32, wc = (wave & 1) * 32;
    int q = lane >> 4, l16 = lane & 15;
    f32x4 acc[2][2] = {};
    const u16* ag = Abf + (size_t)n0*OH;
    const u16* bg0 = Bbf + (size_t)(o0 + wc + l16)*OH + q*8;
    const u16* bg1 = bg0 + (size_t)16*OH;
    for (int k0 = 0; k0 < OH; k0 += 64) {
        #pragma unroll
        for (int p = 0; p < 2; ++p) {
            int sl = p*256 + tid; int rr = sl >> 3, gi = sl & 7, g = gi ^ (rr & 7);
            gl_lds16(ag + (size_t)rr*OH + k0 + g*8, As + sl*8);
        }
        __syncthreads();
        #pragma unroll
        for (int ks = 0; ks < 2; ++ks) {
            int g = ks*4 + q;
            bf16x8 a0 = frag64(As, wr + l16, g);
            bf16x8 a1 = frag64(As, wr + 16 + l16, g);
            bf16x8 b0 = *(const bf16x8*)(bg0 + k0 + ks*32);
            bf16x8 b1 = *(const bf16x8*)(bg1 + k0 + ks*32);
            acc[0][0] = __builtin_amdgcn_mfma_f32_16x16x32_bf16(a0, b0, acc[0][0], 0,0,0);
            acc[0][1] = __builtin_amdgcn_mfma_f32_16x16x32_bf16(a0, b1, acc[0][1], 0,0,0);
            acc[1][0] = __builtin_amdgcn_mfma_f32_16x16x32_bf16(a1, b0, acc[1][0], 0,0,0);
            acc[1][1] = __builtin_amdgcn_mfma_f32_16x16x32_bf16(a1, b1, acc[1][1], 0,0,0);
        }
        __syncthreads();
    }
    float al = alpha[0];
    #pragma unroll
    for (int rt = 0; rt < 2; ++rt) {
        #pragma unroll
        for (int ct = 0; ct < 2; ++ct) {
            int o = o0 + wc + ct*16 + l16;
            float bv = bias[o];
            #pragma unroll
            for (int r = 0; r < 4; ++r) {
                int m = n0 + wr + rt*16 + q*4 + r;
                out[(size_t)m*HH + o] = al * (acc[rt][ct][r] + bv);
            }
        }
    }
}

// ---------------------------------------------------------------------------
extern "C" void kernel_launch(void* const* d_in, const int* in_sizes, int n_in,
                              void* d_out, int out_size, void* d_ws, size_t ws_size,
                              hipStream_t stream) {
    const float* Hj    = (const float*)d_in[0];
    const float* Hi    = (const float*)d_in[1];
    const float* amask = (const float*)d_in[2];
    const float* pjw   = (const float*)d_in[3];
    const float* piw   = (const float*)d_in[4];
    const float* sw1   = (const float*)d_in[5];
    const float* sb1   = (const float*)d_in[6];
    const float* sw2   = (const float*)d_in[7];
    const float* sb2   = (const float*)d_in[8];
    const float* vw1   = (const float*)d_in[9];
    const float* vb1   = (const float*)d_in[10];
    const float* vw2   = (const float*)d_in[11];
    const float* vb2   = (const float*)d_in[12];
    const float* alpha = (const float*)d_in[13];
    float* out = (float*)d_out;
    (void)sb2; // softmax is shift-invariant; sb2 cancels

    u16* bfbase = (u16*)d_ws;
    u16* msginb = bfbase + MB_MSGIN;
    u16* h1b    = bfbase + MB_H1;
    u16* w1b    = bfbase + MB_W1;
    u16* w2b    = bfbase + MB_W2;
    u16* probsb = bfbase + MB_PROBS;
    u16* hitb   = bfbase + MB_HIT;
    u16* zjp    = bfbase + MB_ZJP;
    u16* zip    = bfbase + MB_ZIP;
    u16* wm     = bfbase + MB_WM;
    u16* wab    = bfbase + MB_WAB;
    u16* ab     = bfbase + MB_AB;

    k_wm<<<1, 256, 0, stream>>>(sw1, wm, wab);
    k_prep<<<PHT_END, 256, 0, stream>>>(Hj, Hi, pjw, piw, sb1, vw1, vw2, wab,
                                        w1b, w2b, zjp, zip, ab, hitb);
    k_pair_mfma<<<BB*SS/2, 256, 0, stream>>>(zjp, zip, ab, wm, sw2, amask, probsb);
    k_ctx_mfma<<<dim3(HH/64, SS/64, BB), 256, 0, stream>>>(probsb, hitb, Hj, msginb);
    k_mfma_gemm1<<<dim3(OH/64, BB*SS/64), 256, 0, stream>>>(msginb, w1b, vb1, h1b);
    k_mfma_gemm2<<<dim3(HH/64, BB*SS/64), 256, 0, stream>>>(h1b, w2b, vb2, alpha, out);
}

// Round 9
// 196.752 us; speedup vs baseline: 1.1644x; 1.1644x over previous
//
#include <hip/hip_runtime.h>
#include <hip/hip_bf16.h>
#include <math.h>

#define BB 4
#define SS 512
#define HH 768
#define DD 24
#define MM 96
#define OH 768      // OUT_HID
#define K3H 2304    // 3*H

typedef unsigned short u16;
typedef unsigned int u32;
typedef short bf16x8 __attribute__((ext_vector_type(8)));
typedef float f32x4 __attribute__((ext_vector_type(4)));
typedef u16 u16x4 __attribute__((ext_vector_type(4)));

// bf16 workspace (offsets in u16 from ws base)
#define MB_MSGIN  0                            // [2048][2304]
#define MB_H1     (MB_MSGIN + BB*SS*K3H)       // [2048][768]
#define MB_W1     (MB_H1    + BB*SS*OH)        // [768][2304]
#define MB_W2     (MB_W1    + OH*K3H)          // [768][768]
#define MB_PROBS  (MB_W2    + OH*HH)           // [2048][512]
#define MB_HIT    (MB_PROBS + BB*SS*SS)        // [b][768][512]
#define MB_ZJP    (MB_HIT   + BB*HH*SS)        // [2048][32] bf16, cols>=24 zero
#define MB_ZIP    (MB_ZJP   + BB*SS*32)        // [2048][32]
#define MB_WM     (MB_ZIP   + BB*SS*32)        // [96][96] scorer W
#define MB_WAB    (MB_WM    + MM*96)           // [96][32]  Wa padded
#define MB_AB     (MB_WAB   + MM*32)           // [2048][96] A bf16

__device__ inline u16 f2bf(float x) {
    union { float f; u32 u; } v; v.f = x;
    u32 r = v.u + 0x7fffu + ((v.u >> 16) & 1u);   // RNE
    return (u16)(r >> 16);
}
__device__ inline u32 pk2bf(float lo, float hi) {
    return ((__float_as_uint(lo) + 0x8000u) >> 16) |
           ((__float_as_uint(hi) + 0x8000u) & 0xffff0000u);
}
__device__ inline void unpack8(bf16x8 v, float* f) {
    const u32* d = (const u32*)&v;
    #pragma unroll
    for (int i = 0; i < 4; ++i) {
        f[2*i]   = __uint_as_float(d[i] << 16);
        f[2*i+1] = __uint_as_float(d[i] & 0xffff0000u);
    }
}
__device__ inline void gl_lds16(const u16* g, u16* l) {
    __builtin_amdgcn_global_load_lds(
        (const __attribute__((address_space(1))) void*)g,
        (__attribute__((address_space(3))) void*)l, 16, 0, 0);
}
__device__ inline bf16x8 frag64(const u16* X, int r, int g) {
    return *(const bf16x8*)&X[(r*8 + (g ^ (r & 7)))*8];
}

// ---------------------------------------------------------------------------
// W0: tiny scorer-weight builder (must precede prep's zgemm epilogue)
// ---------------------------------------------------------------------------
__global__ __launch_bounds__(256) void k_wm(
    const float* __restrict__ sw1, u16* __restrict__ Wm, u16* __restrict__ Wab)
{
    for (int i = threadIdx.x; i < MM*96; i += 256) {
        int m = i / 96, k = i % 96;
        float v = 0.f;
        if (k < 24)                 v = sw1[m*96 + 48 + k];         // Wc
        else if (k >= 32 && k < 56) v = sw1[m*96 + 72 + (k - 32)];  // Wd
        else if (k >= 64 && k < 88) v = sw1[m*96 + 24 + (k - 64)];  // Wb
        Wm[i] = f2bf(v);
    }
    for (int i = threadIdx.x; i < MM*32; i += 256) {
        int m = i >> 5, k = i & 31;
        Wab[i] = (k < 24) ? f2bf(sw1[m*96 + k]) : (u16)0;
    }
}

// ---------------------------------------------------------------------------
// PREP (one launch, 1600 blocks):
//  [0,64)      : Z = H@P^T MFMA (j/i) + A epilogue
//  [64,928)    : cast vw1 -> w1b
//  [928,1216)  : cast vw2 -> w2b
//  [1216,1600) : transpose Hi -> HiT bf16 [b][h][t]
// (Hj cast into msgin is fused into k_ctx_mfma's epilogue)
// ---------------------------------------------------------------------------
#define PZ_END   64
#define PC1_END  928
#define PC2_END  1216
#define PHT_END  1600

__global__ __launch_bounds__(256) void k_prep(
    const float* __restrict__ Hj, const float* __restrict__ Hi,
    const float* __restrict__ pjw, const float* __restrict__ piw,
    const float* __restrict__ sb1,
    const float* __restrict__ vw1, const float* __restrict__ vw2,
    const u16* __restrict__ Wab,
    u16* __restrict__ w1b, u16* __restrict__ w2b,
    u16* __restrict__ Zjp, u16* __restrict__ Zip, u16* __restrict__ Ab,
    u16* __restrict__ HiTb)
{
    __shared__ __align__(16) u16 smem[5120];
    int bx = blockIdx.x;
    int tid = threadIdx.x;

    if (bx < PZ_END) {
        int idx = bx;
        int isJ = (idx < 32);
        int n0 = (idx & 31) * 64;
        const float* H = isJ ? Hj : Hi;
        const float* P = isJ ? pjw : piw;
        u16* Zout = isJ ? Zjp : Zip;
        u16* As = smem;
        u16* Bs = smem + 2048;
        u16* zb = smem + 3072;
        int wave = tid >> 6, lane = tid & 63;
        int q = lane >> 4, l16 = lane & 15;

        { int i = tid; Bs[(24 + (i >> 5))*32 + (i & 31)] = 0; }

        int arow = tid >> 2, aseg = tid & 3;
        const float* ah = H + (size_t)(n0 + arow)*HH + aseg*8;
        const float* bh = P + (size_t)arow*HH + aseg*8;
        int adst = arow*32 + ((aseg ^ (arow & 3))*8);

        float4 xa = *(const float4*)(ah);
        float4 ya = *(const float4*)(ah + 4);
        float4 xb = {}, yb = {};
        if (tid < 96) { xb = *(const float4*)(bh); yb = *(const float4*)(bh + 4); }

        f32x4 acc0 = {}, acc1 = {};
        int ga = q ^ (l16 & 3);
        for (int k0 = 0; k0 < HH; k0 += 32) {
            { u32* w = (u32*)&As[adst];
              w[0] = pk2bf(xa.x, xa.y); w[1] = pk2bf(xa.z, xa.w);
              w[2] = pk2bf(ya.x, ya.y); w[3] = pk2bf(ya.z, ya.w); }
            if (tid < 96) {
              u32* w = (u32*)&Bs[adst];
              w[0] = pk2bf(xb.x, xb.y); w[1] = pk2bf(xb.z, xb.w);
              w[2] = pk2bf(yb.x, yb.y); w[3] = pk2bf(yb.z, yb.w); }
            float4 nxa = {}, nya = {}, nxb = {}, nyb = {};
            if (k0 + 32 < HH) {
                nxa = *(const float4*)(ah + k0 + 32);
                nya = *(const float4*)(ah + k0 + 36);
                if (tid < 96) { nxb = *(const float4*)(bh + k0 + 32);
                                nyb = *(const float4*)(bh + k0 + 36); }
            }
            __syncthreads();
            bf16x8 af = *(const bf16x8*)&As[(wave*16 + l16)*32 + ga*8];
            bf16x8 b0 = *(const bf16x8*)&Bs[l16*32 + ga*8];
            bf16x8 b1 = *(const bf16x8*)&Bs[(16 + l16)*32 + ga*8];
            acc0 = __builtin_amdgcn_mfma_f32_16x16x32_bf16(af, b0, acc0, 0,0,0);
            acc1 = __builtin_amdgcn_mfma_f32_16x16x32_bf16(af, b1, acc1, 0,0,0);
            __syncthreads();
            xa = nxa; ya = nya; xb = nxb; yb = nyb;
        }
        #pragma unroll
        for (int r = 0; r < 4; ++r) {
            zb[(wave*16 + q*4 + r)*32 + l16]      = f2bf(acc0[r]);
            zb[(wave*16 + q*4 + r)*32 + 16 + l16] = f2bf(acc1[r]);
        }
        __syncthreads();
        { uint4 v = *(const uint4*)&zb[tid*8];
          *(uint4*)&Zout[(size_t)n0*32 + tid*8] = v; }
        if (isJ) {
            bf16x8 af = *(const bf16x8*)&zb[(wave*16 + l16)*32 + q*8];
            #pragma unroll
            for (int nt = 0; nt < 6; ++nt) {
                bf16x8 bw = *(const bf16x8*)&Wab[(nt*16 + l16)*32 + q*8];
                f32x4 a = {};
                a = __builtin_amdgcn_mfma_f32_16x16x32_bf16(af, bw, a, 0,0,0);
                float bv = sb1[nt*16 + l16];
                #pragma unroll
                for (int r = 0; r < 4; ++r) {
                    int bs = n0 + wave*16 + q*4 + r;
                    Ab[(size_t)bs*MM + nt*16 + l16] = f2bf(a[r] + bv);
                }
            }
        }
    } else if (bx < PC2_END) {
        int idx; const float* src; u16* dst;
        if (bx < PC1_END) { idx = bx - PZ_END;  src = vw1; dst = w1b; }
        else              { idx = bx - PC1_END; src = vw2; dst = w2b; }
        int i = (idx*256 + tid) * 8;
        float4 a = *(const float4*)&src[i];
        float4 c = *(const float4*)&src[i+4];
        u16x4 lo = { f2bf(a.x), f2bf(a.y), f2bf(a.z), f2bf(a.w) };
        u16x4 hi = { f2bf(c.x), f2bf(c.y), f2bf(c.z), f2bf(c.w) };
        *(u16x4*)&dst[i]   = lo;
        *(u16x4*)&dst[i+4] = hi;
    } else {
        int idx = bx - PC2_END;
        int t0 = (idx & 7) * 64;
        int h0 = ((idx >> 3) % 12) * 64;
        int b  = idx / 96;
        u16* tile = smem;                          // 64*74 = 4736 u16
        int r = tid >> 2, cs = tid & 3;
        const float* src = Hi + ((size_t)(b*SS) + t0 + r)*HH + h0 + cs*16;
        u16* dst = &tile[r*74 + cs*16];
        #pragma unroll
        for (int i = 0; i < 4; ++i) {
            float4 v = *(const float4*)(src + i*4);
            *(u32*)&dst[i*4]     = pk2bf(v.x, v.y);
            *(u32*)&dst[i*4 + 2] = pk2bf(v.z, v.w);
        }
        __syncthreads();
        int hr = tid >> 2;
        u16 outv[16];
        #pragma unroll
        for (int i = 0; i < 16; ++i) outv[i] = tile[(cs*16 + i)*74 + hr];
        u16* o = HiTb + ((size_t)b*HH + h0 + hr)*SS + t0 + cs*16;
        *(uint4*)o       = *(const uint4*)&outv[0];
        *(uint4*)(o + 8) = *(const uint4*)&outv[8];
    }
}

// ---------------------------------------------------------------------------
// K2: register-fragment MFMA pairwise scorer + softmax (unchanged).
// ---------------------------------------------------------------------------
__global__ __launch_bounds__(256) void k_pair_mfma(
    const u16* __restrict__ Zjp, const u16* __restrict__ Zip,
    const u16* __restrict__ Ab, const u16* __restrict__ Wm,
    const float* __restrict__ sw2, const float* __restrict__ mask,
    u16* __restrict__ probsb)
{
    int blk = blockIdx.x; int b = blk >> 8; int s0 = (blk & 255) * 2;
    int tid = threadIdx.x, wave = tid >> 6, lane = tid & 63;
    int q = lane >> 4, l16 = lane & 15;
    int si = wave & 1, half = wave >> 1;
    int s = s0 + si, bs = b*SS + s;
    __shared__ __align__(16) u16 ZiS[SS*32];
    __shared__ float logits[2][SS];

    {
        const u16* zb = Zip + (size_t)b*SS*32;
        #pragma unroll
        for (int p = 0; p < 8; ++p) {
            int idx = p*256 + tid;
            int t = idx >> 2, c = idx & 3;
            int g = c ^ ((t + (t >> 2)) & 3);
            gl_lds16(zb + t*32 + g*8, ZiS + idx*8);
        }
    }

    bf16x8 zjf = *(const bf16x8*)&Zjp[(size_t)bs*32 + q*8];
    float zj[8]; unpack8(zjf, zj);
    bf16x8 afc[6], afd[6];
    #pragma unroll
    for (int mt = 0; mt < 6; ++mt) {
        const u16* wrow = &Wm[(mt*16 + l16)*96];
        bf16x8 wcf = *(const bf16x8*)&wrow[q*8];
        afd[mt]    = *(const bf16x8*)&wrow[32 + q*8];
        bf16x8 wbf = *(const bf16x8*)&wrow[64 + q*8];
        float fc[8], fb[8];
        unpack8(wcf, fc); unpack8(wbf, fb);
        u32 aval = (u32)Ab[(size_t)bs*MM + mt*16 + l16];
        union { u32 d[4]; bf16x8 v; } pk;
        #pragma unroll
        for (int i = 0; i < 4; ++i)
            pk.d[i] = pk2bf(fmaf(fc[2*i], zj[2*i], fb[2*i]),
                            fmaf(fc[2*i+1], zj[2*i+1], fb[2*i+1]));
        pk.d[0] = (q == 3) ? aval : pk.d[0];
        afc[mt] = pk.v;
    }
    float w2v[6][4];
    #pragma unroll
    for (int mt = 0; mt < 6; ++mt)
        #pragma unroll
        for (int r = 0; r < 4; ++r) w2v[mt][r] = sw2[mt*16 + q*4 + r];

    __syncthreads();

    for (int k = 0; k < 16; ++k) {
        int t0 = (half*16 + k) * 16;
        int trow = t0 + l16;
        int sw = q ^ ((trow + (trow >> 2)) & 3);
        bf16x8 zif = *(const bf16x8*)&ZiS[trow*32 + sw*8];
        float zi[8]; unpack8(zif, zi);
        union { u32 d[4]; bf16x8 v; } b1, b2;
        #pragma unroll
        for (int i = 0; i < 4; ++i)
            b1.d[i] = pk2bf(fabsf(zj[2*i] - zi[2*i]), fabsf(zj[2*i+1] - zi[2*i+1]));
        b2.v = zif;
        b2.d[0] = (q == 3) ? 0x3F80u : b2.d[0];
        f32x4 acc[6];
        #pragma unroll
        for (int mt = 0; mt < 6; ++mt) {
            f32x4 a = {};
            a = __builtin_amdgcn_mfma_f32_16x16x32_bf16(afc[mt], b2.v, a, 0,0,0);
            a = __builtin_amdgcn_mfma_f32_16x16x32_bf16(afd[mt], b1.v, a, 0,0,0);
            acc[mt] = a;
        }
        float p = 0.f;
        #pragma unroll
        for (int mt = 0; mt < 6; ++mt)
            #pragma unroll
            for (int r = 0; r < 4; ++r)
                p = fmaf(fmaxf(acc[mt][r], 0.f), w2v[mt][r], p);
        p += __shfl_xor(p, 16);
        p += __shfl_xor(p, 32);
        if (lane < 16) logits[si][t0 + lane] = p;
    }
    __syncthreads();

    if (wave < 2) {
        const float NEGF = -3.4028234663852886e38f;
        int bss = b*SS + s0 + wave;
        float l[8], e[8];
        float mx = -INFINITY;
        #pragma unroll
        for (int i = 0; i < 8; ++i) {
            int idx = lane + i*64;
            l[i] = logits[wave][idx] + (1.f - mask[b*SS + idx]) * NEGF;
            mx = fmaxf(mx, l[i]);
        }
        #pragma unroll
        for (int off = 32; off > 0; off >>= 1) mx = fmaxf(mx, __shfl_xor(mx, off));
        float sum = 0.f;
        #pragma unroll
        for (int i = 0; i < 8; ++i) { e[i] = __expf(l[i] - mx); sum += e[i]; }
        #pragma unroll
        for (int off = 32; off > 0; off >>= 1) sum += __shfl_xor(sum, off);
        float inv = 1.f / sum;
        #pragma unroll
        for (int i = 0; i < 8; ++i)
            probsb[(size_t)bss*SS + lane + i*64] = f2bf(e[i] * inv);
    }
}

// ---------------------------------------------------------------------------
// K3: ctx via MFMA, 64x64 tile, BK=64, BOTH operands staged via
// global_load_lds (R6 structure).  Epilogue: LDS remap + fused fp32 Hj read
// -> coalesced writes of all three msgin thirds (ctx | Hj | ctx*Hj).
// ---------------------------------------------------------------------------
__global__ __launch_bounds__(256) void k_ctx_mfma(
    const u16* __restrict__ probsb, const u16* __restrict__ HiTb,
    const float* __restrict__ Hj, u16* __restrict__ msginb)
{
    int b = blockIdx.z;
    int h0 = blockIdx.x * 64;
    int s0 = blockIdx.y * 64;
    int tid = threadIdx.x;
    __shared__ __align__(16) u16 smem[8192];      // As | Bs, reused as zb
    u16* As = smem;
    u16* Bs = smem + 4096;
    int wave = tid >> 6, lane = tid & 63;
    int wr = (wave >> 1) * 32, wc = (wave & 1) * 32;
    int q = lane >> 4, l16 = lane & 15;
    f32x4 acc[2][2] = {};
    const u16* ag = probsb + ((size_t)(b*SS) + s0)*SS;
    const u16* bg = HiTb + ((size_t)b*HH + h0)*SS;
    for (int k0 = 0; k0 < SS; k0 += 64) {
        #pragma unroll
        for (int p = 0; p < 2; ++p) {
            int sl = p*256 + tid; int rr = sl >> 3, gi = sl & 7, g = gi ^ (rr & 7);
            gl_lds16(ag + (size_t)rr*SS + k0 + g*8, As + sl*8);
            gl_lds16(bg + (size_t)rr*SS + k0 + g*8, Bs + sl*8);
        }
        __syncthreads();
        #pragma unroll
        for (int ks = 0; ks < 2; ++ks) {
            int g = ks*4 + q;
            bf16x8 a0 = frag64(As, wr + l16, g);
            bf16x8 a1 = frag64(As, wr + 16 + l16, g);
            bf16x8 b0 = frag64(Bs, wc + l16, g);
            bf16x8 b1 = frag64(Bs, wc + 16 + l16, g);
            acc[0][0] = __builtin_amdgcn_mfma_f32_16x16x32_bf16(a0, b0, acc[0][0], 0,0,0);
            acc[0][1] = __builtin_amdgcn_mfma_f32_16x16x32_bf16(a0, b1, acc[0][1], 0,0,0);
            acc[1][0] = __builtin_amdgcn_mfma_f32_16x16x32_bf16(a1, b0, acc[1][0], 0,0,0);
            acc[1][1] = __builtin_amdgcn_mfma_f32_16x16x32_bf16(a1, b1, acc[1][1], 0,0,0);
        }
        __syncthreads();
    }
    u16* zb = smem;   // stride 72 u16 (16B-aligned rows)
    #pragma unroll
    for (int rt = 0; rt < 2; ++rt)
        #pragma unroll
        for (int ct = 0; ct < 2; ++ct) {
            int hl = wc + ct*16 + l16;
            #pragma unroll
            for (int r = 0; r < 4; ++r)
                zb[(wr + rt*16 + q*4 + r)*72 + hl] = f2bf(acc[rt][ct][r]);
        }
    __syncthreads();
    {
        int s_l = tid >> 2, seg = tid & 3;
        u16 cv[16], hv[16], pv[16];
        *(uint4*)&cv[0] = *(const uint4*)&zb[s_l*72 + seg*16];
        *(uint4*)&cv[8] = *(const uint4*)&zb[s_l*72 + seg*16 + 8];
        int hc = h0 + seg*16;
        const float* hj = Hj + ((size_t)(b*SS) + s0 + s_l)*HH + hc;
        float hf[16];
        #pragma unroll
        for (int i = 0; i < 4; ++i) *(float4*)&hf[i*4] = *(const float4*)(hj + i*4);
        #pragma unroll
        for (int i = 0; i < 8; ++i) {
            float c0 = __uint_as_float((u32)cv[2*i] << 16);
            float c1 = __uint_as_float((u32)cv[2*i+1] << 16);
            u32 hr = pk2bf(hf[2*i], hf[2*i+1]);
            hv[2*i] = (u16)hr; hv[2*i+1] = (u16)(hr >> 16);
            float g0 = __uint_as_float((u32)hv[2*i] << 16);
            float g1 = __uint_as_float((u32)hv[2*i+1] << 16);
            u32 pr = pk2bf(c0*g0, c1*g1);
            pv[2*i] = (u16)pr; pv[2*i+1] = (u16)(pr >> 16);
        }
        u16* row = msginb + (size_t)(b*SS + s0 + s_l)*K3H;
        *(uint4*)&row[hc]            = *(const uint4*)&cv[0];
        *(uint4*)&row[hc + 8]        = *(const uint4*)&cv[8];
        *(uint4*)&row[HH + hc]       = *(const uint4*)&hv[0];
        *(uint4*)&row[HH + hc + 8]   = *(const uint4*)&hv[8];
        *(uint4*)&row[2*HH + hc]     = *(const uint4*)&pv[0];
        *(uint4*)&row[2*HH + hc + 8] = *(const uint4*)&pv[8];
    }
}

// ---------------------------------------------------------------------------
// G1: h1 = relu(msgin @ w1^T + vb1) -> bf16.  64x64 tile, BK=64,
// both operands via global_load_lds (R6 structure).
// ---------------------------------------------------------------------------
__global__ __launch_bounds__(256) void k_mfma_gemm1(
    const u16* __restrict__ Abf, const u16* __restrict__ Bbf,
    const float* __restrict__ bias, u16* __restrict__ Cbf)
{
    int o0 = blockIdx.x * 64;
    int n0 = blockIdx.y * 64;
    int tid = threadIdx.x;
    __shared__ __align__(16) u16 As[64*64];
    __shared__ __align__(16) u16 Bs[64*64];
    int wave = tid >> 6, lane = tid & 63;
    int wr = (wave >> 1) * 32, wc = (wave & 1) * 32;
    int q = lane >> 4, l16 = lane & 15;
    f32x4 acc[2][2] = {};
    const u16* ag = Abf + (size_t)n0*K3H;
    const u16* bg = Bbf + (size_t)o0*K3H;
    for (int k0 = 0; k0 < K3H; k0 += 64) {
        #pragma unroll
        for (int p = 0; p < 2; ++p) {
            int sl = p*256 + tid; int rr = sl >> 3, gi = sl & 7, g = gi ^ (rr & 7);
            gl_lds16(ag + (size_t)rr*K3H + k0 + g*8, As + sl*8);
            gl_lds16(bg + (size_t)rr*K3H + k0 + g*8, Bs + sl*8);
        }
        __syncthreads();
        #pragma unroll
        for (int ks = 0; ks < 2; ++ks) {
            int g = ks*4 + q;
            bf16x8 a0 = frag64(As, wr + l16, g);
            bf16x8 a1 = frag64(As, wr + 16 + l16, g);
            bf16x8 b0 = frag64(Bs, wc + l16, g);
            bf16x8 b1 = frag64(Bs, wc + 16 + l16, g);
            acc[0][0] = __builtin_amdgcn_mfma_f32_16x16x32_bf16(a0, b0, acc[0][0], 0,0,0);
            acc[0][1] = __builtin_amdgcn_mfma_f32_16x16x32_bf16(a0, b1, acc[0][1], 0,0,0);
            acc[1][0] = __builtin_amdgcn_mfma_f32_16x16x32_bf16(a1, b0, acc[1][0], 0,0,0);
            acc[1][1] = __builtin_amdgcn_mfma_f32_16x16x32_bf16(a1, b1, acc[1][1], 0,0,0);
        }
        __syncthreads();
    }
    #pragma unroll
    for (int rt = 0; rt < 2; ++rt) {
        #pragma unroll
        for (int ct = 0; ct < 2; ++ct) {
            int o = o0 + wc + ct*16 + l16;
            float bv = bias[o];
            #pragma unroll
            for (int r = 0; r < 4; ++r) {
                int m = n0 + wr + rt*16 + q*4 + r;
                Cbf[(size_t)m*OH + o] = f2bf(fmaxf(acc[rt][ct][r] + bv, 0.f));
            }
        }
    }
}

// ---------------------------------------------------------------------------
// G2: out = alpha * (h1 @ w2^T + vb2).  64x64 tile, BK=64, both via LDS.
// ---------------------------------------------------------------------------
__global__ __launch_bounds__(256) void k_mfma_gemm2(
    const u16* __restrict__ Abf, const u16* __restrict__ Bbf,
    const float* __restrict__ bias, const float* __restrict__ alpha,
    float* __restrict__ out)
{
    int o0 = blockIdx.x * 64;
    int n0 = blockIdx.y * 64;
    int tid = threadIdx.x;
    __shared__ __align__(16) u16 As[64*64];
    __shared__ __align__(16) u16 Bs[64*64];
    int wave = tid >> 6, lane = tid & 63;
    int wr = (wave >> 1) * 32, wc = (wave & 1) * 32;
    int q = lane >> 4, l16 = lane & 15;
    f32x4 acc[2][2] = {};
    const u16* ag = Abf + (size_t)n0*OH;
    const u16* bg = Bbf + (size_t)o0*OH;
    for (int k0 = 0; k0 < OH; k0 += 64) {
        #pragma unroll
        for (int p = 0; p < 2; ++p) {
            int sl = p*256 + tid; int rr = sl >> 3, gi = sl & 7, g = gi ^ (rr & 7);
            gl_lds16(ag + (size_t)rr*OH + k0 + g*8, As + sl*8);
            gl_lds16(bg + (size_t)rr*OH + k0 + g*8, Bs + sl*8);
        }
        __syncthreads();
        #pragma unroll
        for (int ks = 0; ks < 2; ++ks) {
            int g = ks*4 + q;
            bf16x8 a0 = frag64(As, wr + l16, g);
            bf16x8 a1 = frag64(As, wr + 16 + l16, g);
            bf16x8 b0 = frag64(Bs, wc + l16, g);
            bf16x8 b1 = frag64(Bs, wc + 16 + l16, g);
            acc[0][0] = __builtin_amdgcn_mfma_f32_16x16x32_bf16(a0, b0, acc[0][0], 0,0,0);
            acc[0][1] = __builtin_amdgcn_mfma_f32_16x16x32_bf16(a0, b1, acc[0][1], 0,0,0);
            acc[1][0] = __builtin_amdgcn_mfma_f32_16x16x32_bf16(a1, b0, acc[1][0], 0,0,0);
            acc[1][1] = __builtin_amdgcn_mfma_f32_16x16x32_bf16(a1, b1, acc[1][1], 0,0,0);
        }
        __syncthreads();
    }
    float al = alpha[0];
    #pragma unroll
    for (int rt = 0; rt < 2; ++rt) {
        #pragma unroll
        for (int ct = 0; ct < 2; ++ct) {
            int o = o0 + wc + ct*16 + l16;
            float bv = bias[o];
            #pragma unroll
            for (int r = 0; r < 4; ++r) {
                int m = n0 + wr + rt*16 + q*4 + r;
                out[(size_t)m*HH + o] = al * (acc[rt][ct][r] + bv);
            }
        }
    }
}

// ---------------------------------------------------------------------------
extern "C" void kernel_launch(void* const* d_in, const int* in_sizes, int n_in,
                              void* d_out, int out_size, void* d_ws, size_t ws_size,
                              hipStream_t stream) {
    const float* Hj    = (const float*)d_in[0];
    const float* Hi    = (const float*)d_in[1];
    const float* amask = (const float*)d_in[2];
    const float* pjw   = (const float*)d_in[3];
    const float* piw   = (const float*)d_in[4];
    const float* sw1   = (const float*)d_in[5];
    const float* sb1   = (const float*)d_in[6];
    const float* sw2   = (const float*)d_in[7];
    const float* sb2   = (const float*)d_in[8];
    const float* vw1   = (const float*)d_in[9];
    const float* vb1   = (const float*)d_in[10];
    const float* vw2   = (const float*)d_in[11];
    const float* vb2   = (const float*)d_in[12];
    const float* alpha = (const float*)d_in[13];
    float* out = (float*)d_out;
    (void)sb2; // softmax is shift-invariant; sb2 cancels

    u16* bfbase = (u16*)d_ws;
    u16* msginb = bfbase + MB_MSGIN;
    u16* h1b    = bfbase + MB_H1;
    u16* w1b    = bfbase + MB_W1;
    u16* w2b    = bfbase + MB_W2;
    u16* probsb = bfbase + MB_PROBS;
    u16* hitb   = bfbase + MB_HIT;
    u16* zjp    = bfbase + MB_ZJP;
    u16* zip    = bfbase + MB_ZIP;
    u16* wm     = bfbase + MB_WM;
    u16* wab    = bfbase + MB_WAB;
    u16* ab     = bfbase + MB_AB;

    k_wm<<<1, 256, 0, stream>>>(sw1, wm, wab);
    k_prep<<<PHT_END, 256, 0, stream>>>(Hj, Hi, pjw, piw, sb1, vw1, vw2, wab,
                                        w1b, w2b, zjp, zip, ab, hitb);
    k_pair_mfma<<<BB*SS/2, 256, 0, stream>>>(zjp, zip, ab, wm, sw2, amask, probsb);
    k_ctx_mfma<<<dim3(HH/64, SS/64, BB), 256, 0, stream>>>(probsb, hitb, Hj, msginb);
    k_mfma_gemm1<<<dim3(OH/64, BB*SS/64), 256, 0, stream>>>(msginb, w1b, vb1, h1b);
    k_mfma_gemm2<<<dim3(HH/64, BB*SS/64), 256, 0, stream>>>(h1b, w2b, vb2, alpha, out);
}

// Round 10
// 190.827 us; speedup vs baseline: 1.2006x; 1.0310x over previous
//
#include <hip/hip_runtime.h>
#include <hip/hip_bf16.h>
#include <math.h>

#define BB 4
#define SS 512
#define HH 768
#define DD 24
#define MM 96
#define OH 768      // OUT_HID
#define K3H 2304    // 3*H

typedef unsigned short u16;
typedef unsigned int u32;
typedef short bf16x8 __attribute__((ext_vector_type(8)));
typedef float f32x4 __attribute__((ext_vector_type(4)));
typedef u16 u16x4 __attribute__((ext_vector_type(4)));

// bf16 workspace (offsets in u16 from ws base)
#define MB_MSGIN  0                            // [2048][2304]
#define MB_H1     (MB_MSGIN + BB*SS*K3H)       // [2048][768]
#define MB_W1     (MB_H1    + BB*SS*OH)        // [768][2304]
#define MB_W2     (MB_W1    + OH*K3H)          // [768][768]
#define MB_PROBS  (MB_W2    + OH*HH)           // [2048][512]
#define MB_HIT    (MB_PROBS + BB*SS*SS)        // [b][768][512]
#define MB_ZJP    (MB_HIT   + BB*HH*SS)        // [2048][32] bf16, cols>=24 zero
#define MB_ZIP    (MB_ZJP   + BB*SS*32)        // [2048][32]
#define MB_WM     (MB_ZIP   + BB*SS*32)        // [96][96] scorer W
#define MB_WAB    (MB_WM    + MM*96)           // [96][32]  Wa padded
#define MB_AB     (MB_WAB   + MM*32)           // [2048][96] A bf16

__device__ inline u16 f2bf(float x) {
    union { float f; u32 u; } v; v.f = x;
    u32 r = v.u + 0x7fffu + ((v.u >> 16) & 1u);   // RNE
    return (u16)(r >> 16);
}
__device__ inline u32 pk2bf(float lo, float hi) {
    return ((__float_as_uint(lo) + 0x8000u) >> 16) |
           ((__float_as_uint(hi) + 0x8000u) & 0xffff0000u);
}
__device__ inline void unpack8(bf16x8 v, float* f) {
    const u32* d = (const u32*)&v;
    #pragma unroll
    for (int i = 0; i < 4; ++i) {
        f[2*i]   = __uint_as_float(d[i] << 16);
        f[2*i+1] = __uint_as_float(d[i] & 0xffff0000u);
    }
}
__device__ inline void gl_lds16(const u16* g, u16* l) {
    __builtin_amdgcn_global_load_lds(
        (const __attribute__((address_space(1))) void*)g,
        (__attribute__((address_space(3))) void*)l, 16, 0, 0);
}
__device__ inline bf16x8 frag64(const u16* X, int r, int g) {
    return *(const bf16x8*)&X[(r*8 + (g ^ (r & 7)))*8];
}

// ---------------------------------------------------------------------------
// W0: tiny scorer-weight builder (must precede prep's zgemm epilogue)
// ---------------------------------------------------------------------------
__global__ __launch_bounds__(256) void k_wm(
    const float* __restrict__ sw1, u16* __restrict__ Wm, u16* __restrict__ Wab)
{
    for (int i = threadIdx.x; i < MM*96; i += 256) {
        int m = i / 96, k = i % 96;
        float v = 0.f;
        if (k < 24)                 v = sw1[m*96 + 48 + k];         // Wc
        else if (k >= 32 && k < 56) v = sw1[m*96 + 72 + (k - 32)];  // Wd
        else if (k >= 64 && k < 88) v = sw1[m*96 + 24 + (k - 64)];  // Wb
        Wm[i] = f2bf(v);
    }
    for (int i = threadIdx.x; i < MM*32; i += 256) {
        int m = i >> 5, k = i & 31;
        Wab[i] = (k < 24) ? f2bf(sw1[m*96 + k]) : (u16)0;
    }
}

// ---------------------------------------------------------------------------
// PREP (one launch, 2368 blocks):
//  [0,64)      : Z = H@P^T MFMA (j/i) + A epilogue
//  [64,928)    : cast vw1 -> w1b
//  [928,1216)  : cast vw2 -> w2b
//  [1216,1984) : cast Hj  -> msgin middle third (parallel slack; measured
//                faster here than fused into ctx's epilogue -- R7 vs R9)
//  [1984,2368) : transpose Hi -> HiT bf16 [b][h][t]
// ---------------------------------------------------------------------------
#define PZ_END   64
#define PC1_END  928
#define PC2_END  1216
#define PHJ_END  1984
#define PHT_END  2368

__global__ __launch_bounds__(256) void k_prep(
    const float* __restrict__ Hj, const float* __restrict__ Hi,
    const float* __restrict__ pjw, const float* __restrict__ piw,
    const float* __restrict__ sb1,
    const float* __restrict__ vw1, const float* __restrict__ vw2,
    const u16* __restrict__ Wab,
    u16* __restrict__ w1b, u16* __restrict__ w2b,
    u16* __restrict__ Zjp, u16* __restrict__ Zip, u16* __restrict__ Ab,
    u16* __restrict__ msginb, u16* __restrict__ HiTb)
{
    __shared__ __align__(16) u16 smem[5120];
    int bx = blockIdx.x;
    int tid = threadIdx.x;

    if (bx < PZ_END) {
        int idx = bx;
        int isJ = (idx < 32);
        int n0 = (idx & 31) * 64;
        const float* H = isJ ? Hj : Hi;
        const float* P = isJ ? pjw : piw;
        u16* Zout = isJ ? Zjp : Zip;
        u16* As = smem;
        u16* Bs = smem + 2048;
        u16* zb = smem + 3072;
        int wave = tid >> 6, lane = tid & 63;
        int q = lane >> 4, l16 = lane & 15;

        { int i = tid; Bs[(24 + (i >> 5))*32 + (i & 31)] = 0; }

        int arow = tid >> 2, aseg = tid & 3;
        const float* ah = H + (size_t)(n0 + arow)*HH + aseg*8;
        const float* bh = P + (size_t)arow*HH + aseg*8;
        int adst = arow*32 + ((aseg ^ (arow & 3))*8);

        float4 xa = *(const float4*)(ah);
        float4 ya = *(const float4*)(ah + 4);
        float4 xb = {}, yb = {};
        if (tid < 96) { xb = *(const float4*)(bh); yb = *(const float4*)(bh + 4); }

        f32x4 acc0 = {}, acc1 = {};
        int ga = q ^ (l16 & 3);
        for (int k0 = 0; k0 < HH; k0 += 32) {
            { u32* w = (u32*)&As[adst];
              w[0] = pk2bf(xa.x, xa.y); w[1] = pk2bf(xa.z, xa.w);
              w[2] = pk2bf(ya.x, ya.y); w[3] = pk2bf(ya.z, ya.w); }
            if (tid < 96) {
              u32* w = (u32*)&Bs[adst];
              w[0] = pk2bf(xb.x, xb.y); w[1] = pk2bf(xb.z, xb.w);
              w[2] = pk2bf(yb.x, yb.y); w[3] = pk2bf(yb.z, yb.w); }
            float4 nxa = {}, nya = {}, nxb = {}, nyb = {};
            if (k0 + 32 < HH) {
                nxa = *(const float4*)(ah + k0 + 32);
                nya = *(const float4*)(ah + k0 + 36);
                if (tid < 96) { nxb = *(const float4*)(bh + k0 + 32);
                                nyb = *(const float4*)(bh + k0 + 36); }
            }
            __syncthreads();
            bf16x8 af = *(const bf16x8*)&As[(wave*16 + l16)*32 + ga*8];
            bf16x8 b0 = *(const bf16x8*)&Bs[l16*32 + ga*8];
            bf16x8 b1 = *(const bf16x8*)&Bs[(16 + l16)*32 + ga*8];
            acc0 = __builtin_amdgcn_mfma_f32_16x16x32_bf16(af, b0, acc0, 0,0,0);
            acc1 = __builtin_amdgcn_mfma_f32_16x16x32_bf16(af, b1, acc1, 0,0,0);
            __syncthreads();
            xa = nxa; ya = nya; xb = nxb; yb = nyb;
        }
        #pragma unroll
        for (int r = 0; r < 4; ++r) {
            zb[(wave*16 + q*4 + r)*32 + l16]      = f2bf(acc0[r]);
            zb[(wave*16 + q*4 + r)*32 + 16 + l16] = f2bf(acc1[r]);
        }
        __syncthreads();
        { uint4 v = *(const uint4*)&zb[tid*8];
          *(uint4*)&Zout[(size_t)n0*32 + tid*8] = v; }
        if (isJ) {
            bf16x8 af = *(const bf16x8*)&zb[(wave*16 + l16)*32 + q*8];
            #pragma unroll
            for (int nt = 0; nt < 6; ++nt) {
                bf16x8 bw = *(const bf16x8*)&Wab[(nt*16 + l16)*32 + q*8];
                f32x4 a = {};
                a = __builtin_amdgcn_mfma_f32_16x16x32_bf16(af, bw, a, 0,0,0);
                float bv = sb1[nt*16 + l16];
                #pragma unroll
                for (int r = 0; r < 4; ++r) {
                    int bs = n0 + wave*16 + q*4 + r;
                    Ab[(size_t)bs*MM + nt*16 + l16] = f2bf(a[r] + bv);
                }
            }
        }
    } else if (bx < PC2_END) {
        int idx; const float* src; u16* dst;
        if (bx < PC1_END) { idx = bx - PZ_END;  src = vw1; dst = w1b; }
        else              { idx = bx - PC1_END; src = vw2; dst = w2b; }
        int i = (idx*256 + tid) * 8;
        float4 a = *(const float4*)&src[i];
        float4 c = *(const float4*)&src[i+4];
        u16x4 lo = { f2bf(a.x), f2bf(a.y), f2bf(a.z), f2bf(a.w) };
        u16x4 hi = { f2bf(c.x), f2bf(c.y), f2bf(c.z), f2bf(c.w) };
        *(u16x4*)&dst[i]   = lo;
        *(u16x4*)&dst[i+4] = hi;
    } else if (bx < PHJ_END) {
        int idx = bx - PC2_END;
        int e = (idx*256 + tid) * 8;               // linear over 2048*768
        int n = e / HH, k = e - n*HH;
        float4 a = *(const float4*)&Hj[e];
        float4 c = *(const float4*)&Hj[e+4];
        u16* dst = msginb + (size_t)n*K3H + HH + k;
        u16x4 lo = { f2bf(a.x), f2bf(a.y), f2bf(a.z), f2bf(a.w) };
        u16x4 hi = { f2bf(c.x), f2bf(c.y), f2bf(c.z), f2bf(c.w) };
        *(u16x4*)&dst[0] = lo;
        *(u16x4*)&dst[4] = hi;
    } else {
        int idx = bx - PHJ_END;
        int t0 = (idx & 7) * 64;
        int h0 = ((idx >> 3) % 12) * 64;
        int b  = idx / 96;
        u16* tile = smem;                          // 64*74 = 4736 u16
        int r = tid >> 2, cs = tid & 3;
        const float* src = Hi + ((size_t)(b*SS) + t0 + r)*HH + h0 + cs*16;
        u16* dst = &tile[r*74 + cs*16];
        #pragma unroll
        for (int i = 0; i < 4; ++i) {
            float4 v = *(const float4*)(src + i*4);
            *(u32*)&dst[i*4]     = pk2bf(v.x, v.y);
            *(u32*)&dst[i*4 + 2] = pk2bf(v.z, v.w);
        }
        __syncthreads();
        int hr = tid >> 2;
        u16 outv[16];
        #pragma unroll
        for (int i = 0; i < 16; ++i) outv[i] = tile[(cs*16 + i)*74 + hr];
        u16* o = HiTb + ((size_t)b*HH + h0 + hr)*SS + t0 + cs*16;
        *(uint4*)o       = *(const uint4*)&outv[0];
        *(uint4*)(o + 8) = *(const uint4*)&outv[8];
    }
}

// ---------------------------------------------------------------------------
// K2: register-fragment MFMA pairwise scorer + softmax.
// ---------------------------------------------------------------------------
__global__ __launch_bounds__(256) void k_pair_mfma(
    const u16* __restrict__ Zjp, const u16* __restrict__ Zip,
    const u16* __restrict__ Ab, const u16* __restrict__ Wm,
    const float* __restrict__ sw2, const float* __restrict__ mask,
    u16* __restrict__ probsb)
{
    int blk = blockIdx.x; int b = blk >> 8; int s0 = (blk & 255) * 2;
    int tid = threadIdx.x, wave = tid >> 6, lane = tid & 63;
    int q = lane >> 4, l16 = lane & 15;
    int si = wave & 1, half = wave >> 1;
    int s = s0 + si, bs = b*SS + s;
    __shared__ __align__(16) u16 ZiS[SS*32];
    __shared__ float logits[2][SS];

    {
        const u16* zb = Zip + (size_t)b*SS*32;
        #pragma unroll
        for (int p = 0; p < 8; ++p) {
            int idx = p*256 + tid;
            int t = idx >> 2, c = idx & 3;
            int g = c ^ ((t + (t >> 2)) & 3);
            gl_lds16(zb + t*32 + g*8, ZiS + idx*8);
        }
    }

    bf16x8 zjf = *(const bf16x8*)&Zjp[(size_t)bs*32 + q*8];
    float zj[8]; unpack8(zjf, zj);
    bf16x8 afc[6], afd[6];
    #pragma unroll
    for (int mt = 0; mt < 6; ++mt) {
        const u16* wrow = &Wm[(mt*16 + l16)*96];
        bf16x8 wcf = *(const bf16x8*)&wrow[q*8];
        afd[mt]    = *(const bf16x8*)&wrow[32 + q*8];
        bf16x8 wbf = *(const bf16x8*)&wrow[64 + q*8];
        float fc[8], fb[8];
        unpack8(wcf, fc); unpack8(wbf, fb);
        u32 aval = (u32)Ab[(size_t)bs*MM + mt*16 + l16];
        union { u32 d[4]; bf16x8 v; } pk;
        #pragma unroll
        for (int i = 0; i < 4; ++i)
            pk.d[i] = pk2bf(fmaf(fc[2*i], zj[2*i], fb[2*i]),
                            fmaf(fc[2*i+1], zj[2*i+1], fb[2*i+1]));
        pk.d[0] = (q == 3) ? aval : pk.d[0];
        afc[mt] = pk.v;
    }
    float w2v[6][4];
    #pragma unroll
    for (int mt = 0; mt < 6; ++mt)
        #pragma unroll
        for (int r = 0; r < 4; ++r) w2v[mt][r] = sw2[mt*16 + q*4 + r];

    __syncthreads();

    for (int k = 0; k < 16; ++k) {
        int t0 = (half*16 + k) * 16;
        int trow = t0 + l16;
        int sw = q ^ ((trow + (trow >> 2)) & 3);
        bf16x8 zif = *(const bf16x8*)&ZiS[trow*32 + sw*8];
        float zi[8]; unpack8(zif, zi);
        union { u32 d[4]; bf16x8 v; } b1, b2;
        #pragma unroll
        for (int i = 0; i < 4; ++i)
            b1.d[i] = pk2bf(fabsf(zj[2*i] - zi[2*i]), fabsf(zj[2*i+1] - zi[2*i+1]));
        b2.v = zif;
        b2.d[0] = (q == 3) ? 0x3F80u : b2.d[0];
        f32x4 acc[6];
        #pragma unroll
        for (int mt = 0; mt < 6; ++mt) {
            f32x4 a = {};
            a = __builtin_amdgcn_mfma_f32_16x16x32_bf16(afc[mt], b2.v, a, 0,0,0);
            a = __builtin_amdgcn_mfma_f32_16x16x32_bf16(afd[mt], b1.v, a, 0,0,0);
            acc[mt] = a;
        }
        float p = 0.f;
        #pragma unroll
        for (int mt = 0; mt < 6; ++mt)
            #pragma unroll
            for (int r = 0; r < 4; ++r)
                p = fmaf(fmaxf(acc[mt][r], 0.f), w2v[mt][r], p);
        p += __shfl_xor(p, 16);
        p += __shfl_xor(p, 32);
        if (lane < 16) logits[si][t0 + lane] = p;
    }
    __syncthreads();

    if (wave < 2) {
        const float NEGF = -3.4028234663852886e38f;
        int bss = b*SS + s0 + wave;
        float l[8], e[8];
        float mx = -INFINITY;
        #pragma unroll
        for (int i = 0; i < 8; ++i) {
            int idx = lane + i*64;
            l[i] = logits[wave][idx] + (1.f - mask[b*SS + idx]) * NEGF;
            mx = fmaxf(mx, l[i]);
        }
        #pragma unroll
        for (int off = 32; off > 0; off >>= 1) mx = fmaxf(mx, __shfl_xor(mx, off));
        float sum = 0.f;
        #pragma unroll
        for (int i = 0; i < 8; ++i) { e[i] = __expf(l[i] - mx); sum += e[i]; }
        #pragma unroll
        for (int off = 32; off > 0; off >>= 1) sum += __shfl_xor(sum, off);
        float inv = 1.f / sum;
        #pragma unroll
        for (int i = 0; i < 8; ++i)
            probsb[(size_t)bss*SS + lane + i*64] = f2bf(e[i] * inv);
    }
}

// ---------------------------------------------------------------------------
// K3: ctx via MFMA, 64x64 tile, BK=64, both operands via global_load_lds.
// Epilogue: LDS remap -> coalesced uint4 stores of ctx and ctx*Hj
// (Hj read back bf16 from msgin mid third, written by prep).
// ---------------------------------------------------------------------------
__global__ __launch_bounds__(256) void k_ctx_mfma(
    const u16* __restrict__ probsb, const u16* __restrict__ HiTb,
    u16* __restrict__ msginb)
{
    int b = blockIdx.z;
    int h0 = blockIdx.x * 64;
    int s0 = blockIdx.y * 64;
    int tid = threadIdx.x;
    __shared__ __align__(16) u16 smem[8192];      // As | Bs, reused as zb
    u16* As = smem;
    u16* Bs = smem + 4096;
    int wave = tid >> 6, lane = tid & 63;
    int wr = (wave >> 1) * 32, wc = (wave & 1) * 32;
    int q = lane >> 4, l16 = lane & 15;
    f32x4 acc[2][2] = {};
    const u16* ag = probsb + ((size_t)(b*SS) + s0)*SS;
    const u16* bg = HiTb + ((size_t)b*HH + h0)*SS;
    for (int k0 = 0; k0 < SS; k0 += 64) {
        #pragma unroll
        for (int p = 0; p < 2; ++p) {
            int sl = p*256 + tid; int rr = sl >> 3, gi = sl & 7, g = gi ^ (rr & 7);
            gl_lds16(ag + (size_t)rr*SS + k0 + g*8, As + sl*8);
            gl_lds16(bg + (size_t)rr*SS + k0 + g*8, Bs + sl*8);
        }
        __syncthreads();
        #pragma unroll
        for (int ks = 0; ks < 2; ++ks) {
            int g = ks*4 + q;
            bf16x8 a0 = frag64(As, wr + l16, g);
            bf16x8 a1 = frag64(As, wr + 16 + l16, g);
            bf16x8 b0 = frag64(Bs, wc + l16, g);
            bf16x8 b1 = frag64(Bs, wc + 16 + l16, g);
            acc[0][0] = __builtin_amdgcn_mfma_f32_16x16x32_bf16(a0, b0, acc[0][0], 0,0,0);
            acc[0][1] = __builtin_amdgcn_mfma_f32_16x16x32_bf16(a0, b1, acc[0][1], 0,0,0);
            acc[1][0] = __builtin_amdgcn_mfma_f32_16x16x32_bf16(a1, b0, acc[1][0], 0,0,0);
            acc[1][1] = __builtin_amdgcn_mfma_f32_16x16x32_bf16(a1, b1, acc[1][1], 0,0,0);
        }
        __syncthreads();
    }
    u16* zb = smem;   // stride 72 u16 (16B-aligned rows)
    #pragma unroll
    for (int rt = 0; rt < 2; ++rt)
        #pragma unroll
        for (int ct = 0; ct < 2; ++ct) {
            int hl = wc + ct*16 + l16;
            #pragma unroll
            for (int r = 0; r < 4; ++r)
                zb[(wr + rt*16 + q*4 + r)*72 + hl] = f2bf(acc[rt][ct][r]);
        }
    __syncthreads();
    {
        int s_l = tid >> 2, seg = tid & 3;
        u16 cv[16], hv[16], pv[16];
        *(uint4*)&cv[0] = *(const uint4*)&zb[s_l*72 + seg*16];
        *(uint4*)&cv[8] = *(const uint4*)&zb[s_l*72 + seg*16 + 8];
        u16* row = msginb + (size_t)(b*SS + s0 + s_l)*K3H;
        int hc = h0 + seg*16;
        *(uint4*)&hv[0] = *(const uint4*)&row[HH + hc];
        *(uint4*)&hv[8] = *(const uint4*)&row[HH + hc + 8];
        #pragma unroll
        for (int i = 0; i < 8; ++i) {
            float c0 = __uint_as_float((u32)cv[2*i] << 16);
            float c1 = __uint_as_float((u32)cv[2*i+1] << 16);
            float g0 = __uint_as_float((u32)hv[2*i] << 16);
            float g1 = __uint_as_float((u32)hv[2*i+1] << 16);
            u32 pr = pk2bf(c0*g0, c1*g1);
            pv[2*i] = (u16)pr; pv[2*i+1] = (u16)(pr >> 16);
        }
        *(uint4*)&row[hc]            = *(const uint4*)&cv[0];
        *(uint4*)&row[hc + 8]        = *(const uint4*)&cv[8];
        *(uint4*)&row[2*HH + hc]     = *(const uint4*)&pv[0];
        *(uint4*)&row[2*HH + hc + 8] = *(const uint4*)&pv[8];
    }
}

// ---------------------------------------------------------------------------
// G1: h1 = relu(msgin @ w1^T + vb1) -> bf16.  64x64 tile, BK=64,
// both operands via global_load_lds.
// ---------------------------------------------------------------------------
__global__ __launch_bounds__(256) void k_mfma_gemm1(
    const u16* __restrict__ Abf, const u16* __restrict__ Bbf,
    const float* __restrict__ bias, u16* __restrict__ Cbf)
{
    int o0 = blockIdx.x * 64;
    int n0 = blockIdx.y * 64;
    int tid = threadIdx.x;
    __shared__ __align__(16) u16 As[64*64];
    __shared__ __align__(16) u16 Bs[64*64];
    int wave = tid >> 6, lane = tid & 63;
    int wr = (wave >> 1) * 32, wc = (wave & 1) * 32;
    int q = lane >> 4, l16 = lane & 15;
    f32x4 acc[2][2] = {};
    const u16* ag = Abf + (size_t)n0*K3H;
    const u16* bg = Bbf + (size_t)o0*K3H;
    for (int k0 = 0; k0 < K3H; k0 += 64) {
        #pragma unroll
        for (int p = 0; p < 2; ++p) {
            int sl = p*256 + tid; int rr = sl >> 3, gi = sl & 7, g = gi ^ (rr & 7);
            gl_lds16(ag + (size_t)rr*K3H + k0 + g*8, As + sl*8);
            gl_lds16(bg + (size_t)rr*K3H + k0 + g*8, Bs + sl*8);
        }
        __syncthreads();
        #pragma unroll
        for (int ks = 0; ks < 2; ++ks) {
            int g = ks*4 + q;
            bf16x8 a0 = frag64(As, wr + l16, g);
            bf16x8 a1 = frag64(As, wr + 16 + l16, g);
            bf16x8 b0 = frag64(Bs, wc + l16, g);
            bf16x8 b1 = frag64(Bs, wc + 16 + l16, g);
            acc[0][0] = __builtin_amdgcn_mfma_f32_16x16x32_bf16(a0, b0, acc[0][0], 0,0,0);
            acc[0][1] = __builtin_amdgcn_mfma_f32_16x16x32_bf16(a0, b1, acc[0][1], 0,0,0);
            acc[1][0] = __builtin_amdgcn_mfma_f32_16x16x32_bf16(a1, b0, acc[1][0], 0,0,0);
            acc[1][1] = __builtin_amdgcn_mfma_f32_16x16x32_bf16(a1, b1, acc[1][1], 0,0,0);
        }
        __syncthreads();
    }
    #pragma unroll
    for (int rt = 0; rt < 2; ++rt) {
        #pragma unroll
        for (int ct = 0; ct < 2; ++ct) {
            int o = o0 + wc + ct*16 + l16;
            float bv = bias[o];
            #pragma unroll
            for (int r = 0; r < 4; ++r) {
                int m = n0 + wr + rt*16 + q*4 + r;
                Cbf[(size_t)m*OH + o] = f2bf(fmaxf(acc[rt][ct][r] + bv, 0.f));
            }
        }
    }
}

// ---------------------------------------------------------------------------
// G2: out = alpha * (h1 @ w2^T + vb2).  64x64 tile, BK=64, both via LDS.
// ---------------------------------------------------------------------------
__global__ __launch_bounds__(256) void k_mfma_gemm2(
    const u16* __restrict__ Abf, const u16* __restrict__ Bbf,
    const float* __restrict__ bias, const float* __restrict__ alpha,
    float* __restrict__ out)
{
    int o0 = blockIdx.x * 64;
    int n0 = blockIdx.y * 64;
    int tid = threadIdx.x;
    __shared__ __align__(16) u16 As[64*64];
    __shared__ __align__(16) u16 Bs[64*64];
    int wave = tid >> 6, lane = tid & 63;
    int wr = (wave >> 1) * 32, wc = (wave & 1) * 32;
    int q = lane >> 4, l16 = lane & 15;
    f32x4 acc[2][2] = {};
    const u16* ag = Abf + (size_t)n0*OH;
    const u16* bg = Bbf + (size_t)o0*OH;
    for (int k0 = 0; k0 < OH; k0 += 64) {
        #pragma unroll
        for (int p = 0; p < 2; ++p) {
            int sl = p*256 + tid; int rr = sl >> 3, gi = sl & 7, g = gi ^ (rr & 7);
            gl_lds16(ag + (size_t)rr*OH + k0 + g*8, As + sl*8);
            gl_lds16(bg + (size_t)rr*OH + k0 + g*8, Bs + sl*8);
        }
        __syncthreads();
        #pragma unroll
        for (int ks = 0; ks < 2; ++ks) {
            int g = ks*4 + q;
            bf16x8 a0 = frag64(As, wr + l16, g);
            bf16x8 a1 = frag64(As, wr + 16 + l16, g);
            bf16x8 b0 = frag64(Bs, wc + l16, g);
            bf16x8 b1 = frag64(Bs, wc + 16 + l16, g);
            acc[0][0] = __builtin_amdgcn_mfma_f32_16x16x32_bf16(a0, b0, acc[0][0], 0,0,0);
            acc[0][1] = __builtin_amdgcn_mfma_f32_16x16x32_bf16(a0, b1, acc[0][1], 0,0,0);
            acc[1][0] = __builtin_amdgcn_mfma_f32_16x16x32_bf16(a1, b0, acc[1][0], 0,0,0);
            acc[1][1] = __builtin_amdgcn_mfma_f32_16x16x32_bf16(a1, b1, acc[1][1], 0,0,0);
        }
        __syncthreads();
    }
    float al = alpha[0];
    #pragma unroll
    for (int rt = 0; rt < 2; ++rt) {
        #pragma unroll
        for (int ct = 0; ct < 2; ++ct) {
            int o = o0 + wc + ct*16 + l16;
            float bv = bias[o];
            #pragma unroll
            for (int r = 0; r < 4; ++r) {
                int m = n0 + wr + rt*16 + q*4 + r;
                out[(size_t)m*HH + o] = al * (acc[rt][ct][r] + bv);
            }
        }
    }
}

// ---------------------------------------------------------------------------
extern "C" void kernel_launch(void* const* d_in, const int* in_sizes, int n_in,
                              void* d_out, int out_size, void* d_ws, size_t ws_size,
                              hipStream_t stream) {
    const float* Hj    = (const float*)d_in[0];
    const float* Hi    = (const float*)d_in[1];
    const float* amask = (const float*)d_in[2];
    const float* pjw   = (const float*)d_in[3];
    const float* piw   = (const float*)d_in[4];
    const float* sw1   = (const float*)d_in[5];
    const float* sb1   = (const float*)d_in[6];
    const float* sw2   = (const float*)d_in[7];
    const float* sb2   = (const float*)d_in[8];
    const float* vw1   = (const float*)d_in[9];
    const float* vb1   = (const float*)d_in[10];
    const float* vw2   = (const float*)d_in[11];
    const float* vb2   = (const float*)d_in[12];
    const float* alpha = (const float*)d_in[13];
    float* out = (float*)d_out;
    (void)sb2; // softmax is shift-invariant; sb2 cancels

    u16* bfbase = (u16*)d_ws;
    u16* msginb = bfbase + MB_MSGIN;
    u16* h1b    = bfbase + MB_H1;
    u16* w1b    = bfbase + MB_W1;
    u16* w2b    = bfbase + MB_W2;
    u16* probsb = bfbase + MB_PROBS;
    u16* hitb   = bfbase + MB_HIT;
    u16* zjp    = bfbase + MB_ZJP;
    u16* zip    = bfbase + MB_ZIP;
    u16* wm     = bfbase + MB_WM;
    u16* wab    = bfbase + MB_WAB;
    u16* ab     = bfbase + MB_AB;

    k_wm<<<1, 256, 0, stream>>>(sw1, wm, wab);
    k_prep<<<PHT_END, 256, 0, stream>>>(Hj, Hi, pjw, piw, sb1, vw1, vw2, wab,
                                        w1b, w2b, zjp, zip, ab, msginb, hitb);
    k_pair_mfma<<<BB*SS/2, 256, 0, stream>>>(zjp, zip, ab, wm, sw2, amask, probsb);
    k_ctx_mfma<<<dim3(HH/64, SS/64, BB), 256, 0, stream>>>(probsb, hitb, msginb);
    k_mfma_gemm1<<<dim3(OH/64, BB*SS/64), 256, 0, stream>>>(msginb, w1b, vb1, h1b);
    k_mfma_gemm2<<<dim3(HH/64, BB*SS/64), 256, 0, stream>>>(h1b, w2b, vb2, alpha, out);
}